// Round 2
// baseline (221.121 us; speedup 1.0000x reference)
//
#include <hip/hip_runtime.h>

#define MM    32768
#define TPB   256
#define RPT   16                  // output bins per thread
#define TILE  (TPB * RPT)         // 4096 bins per tile
#define NTILE ((2 * MM) / TILE)   // 16 tiles
#define CHUNK 256                 // i-values per (tile,chunk) pair
#define WIN   (TILE + CHUNK)      // 4352 dwords of B window
#define NPAIR 1152                // sum over tiles of chunk counts

// LDS chunk swizzle: chunk index c -> c ^ ((c>>3)&3). In dword terms
// (chunk = s>>2, within-chunk = s&3): s' = s ^ ((s>>3)&12). XORs chunk
// bits 0-1 (s bits 2-3) with chunk bits 3-4 -> a uint4 stays contiguous
// and 16B-aligned. Read pattern is chunk = 4*t + const per lane (16-way
// bank alias unswizzled); swizzled, 8 consecutive lanes cover all 32 banks.
__device__ __forceinline__ int swz(int s) { return s ^ ((s >> 3) & 12); }

// C[k] += sum over this chunk's i of A[i]*B[k-i], accumulated mod 2^32.
// Pair = (tile, chunk): tile owns bins [k0, k0+TILE); chunk covers
// i in [i0, i0+CHUNK). bSh[s] = B[base+s], base = k0-i0-(CHUNK-1),
// zero-padded outside [0,MM). Thread t owns bins k0+RPT*t+r.
// acc[r] += aSh[255-kp] * bSh[RPT*t + r + kp], kp = 0..255.
// Per 4-kp group: one new b128 window read feeds 64 mad_u32_u24.
__global__ __launch_bounds__(TPB) void conv_kernel(
    const int* __restrict__ A, const int* __restrict__ B,
    unsigned* __restrict__ out)
{
    __shared__ __align__(16) unsigned bSh[WIN];
    __shared__ __align__(16) unsigned aSh[CHUNK];

    // Decode flat pair id -> (tile, chunkOff). count(t) = t<8 ? 16(t+1) : 16(16-t).
    int id = (int)blockIdx.x;
    int tile = 0;
#pragma unroll 1
    for (; tile < NTILE - 1; ++tile) {
        const int cnt = (tile < NTILE / 2) ? RPT * (tile + 1) : RPT * (NTILE - tile);
        if (id < cnt) break;
        id -= cnt;
    }

    const int k0 = tile * TILE;
    int iMin = k0 - (MM - 1); if (iMin < 0) iMin = 0;
    const int c0 = iMin >> 8;
    const int i0 = (c0 + id) << 8;
    const int base = k0 - i0 - (CHUNK - 1);
    const int t = (int)threadIdx.x;

    // Stage B window (zero-padded) and A chunk.
#pragma unroll
    for (int s = t; s < WIN; s += TPB) {  // 17 iterations, uniform
        const int j = base + s;
        bSh[swz(s)] = (j >= 0 && j < MM) ? (unsigned)B[j] : 0u;
    }
    aSh[t] = (unsigned)A[i0 + t];
    __syncthreads();

    const int bd = RPT * t;  // thread's logical dword base in bSh
    uint4 w0 = *(const uint4*)&bSh[swz(bd + 0)];
    uint4 w1 = *(const uint4*)&bSh[swz(bd + 4)];
    uint4 w2 = *(const uint4*)&bSh[swz(bd + 8)];
    uint4 w3 = *(const uint4*)&bSh[swz(bd + 12)];

    unsigned acc[RPT];
#pragma unroll
    for (int r = 0; r < RPT; ++r) acc[r] = 0u;

#pragma unroll 4
    for (int g = 0; g < CHUNK / 4; ++g) {  // 64 groups of 4 kp
        const uint4 w4 = *(const uint4*)&bSh[swz(bd + 4 * g + 16)];
        const uint4 av = *(const uint4*)&aSh[CHUNK - 4 - 4 * g];  // broadcast
        const unsigned aa[4] = {av.w, av.z, av.y, av.x};  // aa[d] = A[i0+255-4g-d]
        const unsigned bb[20] = {w0.x, w0.y, w0.z, w0.w,
                                 w1.x, w1.y, w1.z, w1.w,
                                 w2.x, w2.y, w2.z, w2.w,
                                 w3.x, w3.y, w3.z, w3.w,
                                 w4.x, w4.y, w4.z, w4.w};
#pragma unroll
        for (int d = 0; d < 4; ++d) {
#pragma unroll
            for (int r = 0; r < RPT; ++r) {
                acc[r] += __umul24(aa[d], bb[d + r]);  // v_mad_u32_u24, exact mod 2^32
            }
        }
        w0 = w1; w1 = w2; w2 = w3; w3 = w4;
    }

    // Accumulate into output (u32 atomics; wrap == mod 2^32, order-independent).
    unsigned* o = out + k0 + bd;
#pragma unroll
    for (int r = 0; r < RPT; ++r) {
        atomicAdd(&o[r], acc[r]);
    }
}

extern "C" void kernel_launch(void* const* d_in, const int* in_sizes, int n_in,
                              void* d_out, int out_size, void* d_ws, size_t ws_size,
                              hipStream_t stream)
{
    const int* A = (const int*)d_in[0];
    const int* B = (const int*)d_in[1];
    unsigned* out = (unsigned*)d_out;

    hipMemsetAsync(d_out, 0, (size_t)out_size * sizeof(int), stream);
    conv_kernel<<<NPAIR, TPB, 0, stream>>>(A, B, out);
}

// Round 3
// 121.722 us; speedup vs baseline: 1.8166x; 1.8166x over previous
//
#include <hip/hip_runtime.h>

#define MM    32768
#define TPB   256
#define RPT   8                   // output bins per thread
#define TILE  (TPB * RPT)         // 2048 bins per tile
#define NTILE ((2 * MM) / TILE)   // 32 tiles
#define CHUNK 256                 // i-values per block
#define WIN   (TILE + CHUNK)      // 2304 dwords of B window
#define NPAIR 2176                // total (tile, chunk) pairs

// LDS dword swizzle: XOR dword bits 5-7 into bank bits 2-4. Bijective within
// every 32-dword block (WIN is 32-aligned), preserves 16B quad alignment
// (only bits >=2 change, whole quads move together).
__device__ __forceinline__ int swz(int s) { return s ^ ((s >> 3) & 0x1C); }

// C[k] += sum over this chunk's i of A[i]*B[k-i], accumulated mod 2^32
// (u32 wrap == the int32 the harness compares against; order-independent).
// Thread t owns bins k = k0 + 8t + r, r in [0,8).
//   acc_r += A[i0+255-(4g+d)] * bSh[8t + 4g + d + r],  g=0..63, d=0..3
// A index is wave-uniform -> scalar loads; one new b128 window read per g
// feeds 32 v_mad_u32_u24.
#define MACROW(a, b0,b1,b2,b3,b4,b5,b6,b7)                                   \
    acc0 += __umul24(a, b0); acc1 += __umul24(a, b1);                        \
    acc2 += __umul24(a, b2); acc3 += __umul24(a, b3);                        \
    acc4 += __umul24(a, b4); acc5 += __umul24(a, b5);                        \
    acc6 += __umul24(a, b6); acc7 += __umul24(a, b7);

__global__ __launch_bounds__(TPB) void conv_kernel(
    const int* __restrict__ A, const int* __restrict__ B,
    unsigned* __restrict__ out)
{
    __shared__ __align__(16) unsigned bSh[WIN];

    // Decode flat pair id -> (tile, chunk offset). Scalar loop, <=31 iters.
    int id = (int)blockIdx.x;
    int tile = 0;
#pragma unroll 1
    for (; tile < NTILE - 1; ++tile) {
        const int cnt = (tile < NTILE / 2) ? RPT * (tile + 1) : RPT * (NTILE - tile);
        if (id < cnt) break;
        id -= cnt;
    }

    const int k0 = tile * TILE;
    int iMin = k0 - (MM - 1); if (iMin < 0) iMin = 0;
    const int i0 = ((iMin >> 8) + id) << 8;      // chunk base, in [0, MM-256]
    const int base = k0 - i0 - (CHUNK - 1);
    const int t = (int)threadIdx.x;

    // Stage B window (zero-padded at triangle edges), swizzled. 9 uniform iters.
#pragma unroll
    for (int s = t; s < WIN; s += TPB) {
        const int j = base + s;
        bSh[swz(s)] = (j >= 0 && j < MM) ? (unsigned)B[j] : 0u;
    }
    __syncthreads();

    const int bd = RPT * t;  // thread's logical dword base in the window
    uint4 wa = *(const uint4*)&bSh[swz(bd + 0)];   // logical b0..b3
    uint4 wb = *(const uint4*)&bSh[swz(bd + 4)];   // logical b4..b7

    unsigned acc0 = 0, acc1 = 0, acc2 = 0, acc3 = 0;
    unsigned acc4 = 0, acc5 = 0, acc6 = 0, acc7 = 0;

    const int* Ap = A + i0 + CHUNK - 4;  // Ap[3-d] = A[i0+255-4g-d]; steps -4

#pragma unroll 4
    for (int g = 0; g < CHUNK / 4; ++g) {
        const uint4 wc = *(const uint4*)&bSh[swz(bd + 4 * g + 8)];  // b8..b11
        // Wave-uniform A values -> SGPRs.
        const unsigned a0 = (unsigned)Ap[3];
        const unsigned a1 = (unsigned)Ap[2];
        const unsigned a2 = (unsigned)Ap[1];
        const unsigned a3 = (unsigned)Ap[0];
        Ap -= 4;

        MACROW(a0, wa.x, wa.y, wa.z, wa.w, wb.x, wb.y, wb.z, wb.w);   // d=0
        MACROW(a1, wa.y, wa.z, wa.w, wb.x, wb.y, wb.z, wb.w, wc.x);   // d=1
        MACROW(a2, wa.z, wa.w, wb.x, wb.y, wb.z, wb.w, wc.x, wc.y);   // d=2
        MACROW(a3, wa.w, wb.x, wb.y, wb.z, wb.w, wc.x, wc.y, wc.z);   // d=3

        wa = wb; wb = wc;
    }

    // Accumulate into output; u32 atomic wrap is exact mod 2^32.
    unsigned* o = out + k0 + bd;
    atomicAdd(&o[0], acc0); atomicAdd(&o[1], acc1);
    atomicAdd(&o[2], acc2); atomicAdd(&o[3], acc3);
    atomicAdd(&o[4], acc4); atomicAdd(&o[5], acc5);
    atomicAdd(&o[6], acc6); atomicAdd(&o[7], acc7);
}

extern "C" void kernel_launch(void* const* d_in, const int* in_sizes, int n_in,
                              void* d_out, int out_size, void* d_ws, size_t ws_size,
                              hipStream_t stream)
{
    const int* A = (const int*)d_in[0];
    const int* B = (const int*)d_in[1];
    unsigned* out = (unsigned*)d_out;

    hipMemsetAsync(d_out, 0, (size_t)out_size * sizeof(int), stream);
    conv_kernel<<<NPAIR, TPB, 0, stream>>>(A, B, out);
}

// Round 4
// 82.807 us; speedup vs baseline: 2.6703x; 1.4699x over previous
//
#include <hip/hip_runtime.h>

#define MM     32768
#define TPB    256
#define RPT    8                   // output bins per thread
#define TILE   (TPB * RPT)         // 2048 bins per tile
#define NTILE  ((2 * MM) / TILE)   // 32 tiles
#define CHUNK  256                 // i-values per chunk
#define CPB    2                   // chunks per block (register-accumulated)
#define WIN    (TILE + CHUNK)      // 2304 dwords of B window
#define NPAIR2 1088                // total (tile, chunk-group) blocks

// Per-tile chunk-group count: cnt2_t = 4(t+1) for t<16 else 4(32-t); sum=1088.
__device__ __forceinline__ int cnt2_of(int t) {
    return (t < NTILE / 2) ? 4 * (t + 1) : 4 * (NTILE - t);
}

// LDS dword swizzle: XOR dword bits 5-7 into bank bits 2-4. Bijective within
// every 32-dword block, preserves 16B quad alignment.
__device__ __forceinline__ int swz(int s) { return s ^ ((s >> 3) & 0x1C); }

// acc_r += A[i0+255-(4g+d)] * bSh[8t + 4g + d + r] accumulated mod 2^32
// (u32 wrap == the int32 the harness compares; order-independent, exact).
#define MACROW(a, b0,b1,b2,b3,b4,b5,b6,b7)                                   \
    acc0 += __umul24(a, b0); acc1 += __umul24(a, b1);                        \
    acc2 += __umul24(a, b2); acc3 += __umul24(a, b3);                        \
    acc4 += __umul24(a, b4); acc5 += __umul24(a, b5);                        \
    acc6 += __umul24(a, b6); acc7 += __umul24(a, b7);

template <bool PARTIAL>
__global__ __launch_bounds__(TPB) void conv_kernel(
    const int* __restrict__ A, const int* __restrict__ B,
    unsigned* __restrict__ ws, unsigned* __restrict__ out)
{
    __shared__ __align__(16) unsigned bSh[WIN];

    // Decode flat block id -> (tile, chunk-group offset). Scalar, <=31 iters.
    int id = (int)blockIdx.x;
    int tile = 0;
#pragma unroll 1
    for (; tile < NTILE - 1; ++tile) {
        const int cnt = cnt2_of(tile);
        if (id < cnt) break;
        id -= cnt;
    }

    const int k0 = tile * TILE;
    int iMin = k0 - (MM - 1); if (iMin < 0) iMin = 0;
    const int c0 = iMin >> 8;
    const int t = (int)threadIdx.x;
    const int bd = RPT * t;  // thread's logical dword base in the window

    unsigned acc0 = 0, acc1 = 0, acc2 = 0, acc3 = 0;
    unsigned acc4 = 0, acc5 = 0, acc6 = 0, acc7 = 0;

#pragma unroll 1
    for (int cc = 0; cc < CPB; ++cc) {
        const int i0 = (c0 + CPB * id + cc) << 8;  // chunk base
        const int base = k0 - i0 - (CHUNK - 1);

        if (cc) __syncthreads();  // previous MAC readers done before restage
#pragma unroll
        for (int s = t; s < WIN; s += TPB) {  // 9 uniform iterations
            const int j = base + s;
            bSh[swz(s)] = (j >= 0 && j < MM) ? (unsigned)B[j] : 0u;
        }
        __syncthreads();

        uint4 wa = *(const uint4*)&bSh[swz(bd + 0)];
        uint4 wb = *(const uint4*)&bSh[swz(bd + 4)];
        const int* Ap = A + i0 + CHUNK - 4;  // wave-uniform -> s_load

#pragma unroll 4
        for (int g = 0; g < CHUNK / 4; ++g) {
            const uint4 wc = *(const uint4*)&bSh[swz(bd + 4 * g + 8)];
            const unsigned a0 = (unsigned)Ap[3];
            const unsigned a1 = (unsigned)Ap[2];
            const unsigned a2 = (unsigned)Ap[1];
            const unsigned a3 = (unsigned)Ap[0];
            Ap -= 4;

            MACROW(a0, wa.x, wa.y, wa.z, wa.w, wb.x, wb.y, wb.z, wb.w);
            MACROW(a1, wa.y, wa.z, wa.w, wb.x, wb.y, wb.z, wb.w, wc.x);
            MACROW(a2, wa.z, wa.w, wb.x, wb.y, wb.z, wb.w, wc.x, wc.y);
            MACROW(a3, wa.w, wb.x, wb.y, wb.z, wb.w, wc.x, wc.y, wc.z);

            wa = wb; wb = wc;
        }
    }

    if (PARTIAL) {
        // Private partial slice: plain coalesced stores, no contention.
        unsigned* w = ws + (size_t)blockIdx.x * TILE + bd;
        *(uint4*)&w[0] = make_uint4(acc0, acc1, acc2, acc3);
        *(uint4*)&w[4] = make_uint4(acc4, acc5, acc6, acc7);
    } else {
        unsigned* o = out + k0 + bd;
        atomicAdd(&o[0], acc0); atomicAdd(&o[1], acc1);
        atomicAdd(&o[2], acc2); atomicAdd(&o[3], acc3);
        atomicAdd(&o[4], acc4); atomicAdd(&o[5], acc5);
        atomicAdd(&o[6], acc6); atomicAdd(&o[7], acc7);
    }
}

// out[k] = sum over the owning tile's partial slices (mod 2^32).
__global__ __launch_bounds__(TPB) void reduce_kernel(
    const unsigned* __restrict__ ws, unsigned* __restrict__ out)
{
    const int k = (int)blockIdx.x * TPB + (int)threadIdx.x;
    const int tile = k >> 11;

    int base2 = 0;
#pragma unroll 1
    for (int s = 0; s < NTILE - 1; ++s) {  // wave-uniform scalar loop
        if (s >= tile) break;
        base2 += cnt2_of(s);
    }
    const int cnt2 = cnt2_of(tile);

    const unsigned* p = ws + (size_t)base2 * TILE + (k & (TILE - 1));
    unsigned sum = 0;
#pragma unroll 4
    for (int c = 0; c < cnt2; ++c) sum += p[(size_t)c * TILE];
    out[k] = sum;
}

extern "C" void kernel_launch(void* const* d_in, const int* in_sizes, int n_in,
                              void* d_out, int out_size, void* d_ws, size_t ws_size,
                              hipStream_t stream)
{
    const int* A = (const int*)d_in[0];
    const int* B = (const int*)d_in[1];
    unsigned* out = (unsigned*)d_out;

    const size_t need = (size_t)NPAIR2 * TILE * sizeof(unsigned);  // 8.9 MB
    if (ws_size >= need) {
        unsigned* ws = (unsigned*)d_ws;
        conv_kernel<true><<<NPAIR2, TPB, 0, stream>>>(A, B, ws, out);
        reduce_kernel<<<(2 * MM) / TPB, TPB, 0, stream>>>(ws, out);
    } else {
        hipMemsetAsync(d_out, 0, (size_t)out_size * sizeof(int), stream);
        conv_kernel<false><<<NPAIR2, TPB, 0, stream>>>(A, B, nullptr, out);
    }
}

// Round 5
// 44.741 us; speedup vs baseline: 4.9423x; 1.8508x over previous
//
#include <hip/hip_runtime.h>

#define MM     32768
#define TPB    256
#define RPT    8                    // bins per thread
#define TILE   2048                 // bins per tile
#define NTILE  32
#define CHUNK  256                  // i-limbs per chunk (=128 pairs)
#define NPACK  (MM / 2 + 1)         // 16385 packed entries (edge pad)
#define WINP   1152                 // live window dwords per parity
#define WPAD   1160                 // + prefetch overread pad
#define PA_OFS 0                    // ws dword offsets
#define PE_OFS (MM / 2)             // 16384
#define PO_OFS (PE_OFS + NPACK)     // 32769
#define P_OFS  49408                // partials base (256-aligned dwords)

// Per-tile chunk count: 8(t+1) for t<16 else 8(32-t); sum = 2176.
__device__ __host__ __forceinline__ int cnt_of(int t) {
    return (t < NTILE / 2) ? 8 * (t + 1) : 8 * (NTILE - t);
}

typedef unsigned short ushort2e __attribute__((ext_vector_type(2)));

// 2 exact u16 MACs, accumulated mod 2^32 (wrap == the int32 the harness compares).
__device__ __forceinline__ unsigned DOT2(unsigned a, unsigned b, unsigned c) {
#if __has_builtin(__builtin_amdgcn_udot2)
    return __builtin_amdgcn_udot2(__builtin_bit_cast(ushort2e, a),
                                  __builtin_bit_cast(ushort2e, b), c, false);
#else
    return c + (a & 0xFFFFu) * (b & 0xFFFFu) + (a >> 16) * (b >> 16);
#endif
}

// PA[m]=(lo A[2m], hi A[2m+1]); PE[n]=(lo B[2n], hi B[2n-1]); PO[n]=(lo B[2n+1], hi B[2n]).
__global__ __launch_bounds__(TPB) void pack_kernel(
    const int* __restrict__ A, const int* __restrict__ B, unsigned* __restrict__ ws)
{
    const int e = (int)blockIdx.x * TPB + (int)threadIdx.x;
    if (e < MM / 2)
        ws[PA_OFS + e] = (unsigned)A[2 * e] | ((unsigned)A[2 * e + 1] << 16);
    if (e < NPACK) {
        const unsigned elo = (e < MM / 2) ? (unsigned)B[2 * e] : 0u;
        const unsigned ehi = (e >= 1) ? (unsigned)B[2 * e - 1] : 0u;
        ws[PE_OFS + e] = elo | (ehi << 16);
        unsigned olo = 0u, ohi = 0u;
        if (e < MM / 2) { olo = (unsigned)B[2 * e + 1]; ohi = (unsigned)B[2 * e]; }
        ws[PO_OFS + e] = olo | (ohi << 16);
    }
}

// Even bin k=2K: acc += dot2(PA[m], PE[K-m]); odd k=2K+1: dot2(PA[m], PO[K-m]).
// Window local index = 4t + r/2 + m' (m' = Am0 - m), base n0 = k0/2 - i0/2 - 127.
#define STEP(a, e0, e1, e2, e3, o0, o1, o2, o3)                                  \
    acc0 = DOT2(a, e0, acc0); acc2 = DOT2(a, e1, acc2);                          \
    acc4 = DOT2(a, e2, acc4); acc6 = DOT2(a, e3, acc6);                          \
    acc1 = DOT2(a, o0, acc1); acc3 = DOT2(a, o1, acc3);                          \
    acc5 = DOT2(a, o2, acc5); acc7 = DOT2(a, o3, acc7);

#define GROUP(G, Ex, Ey, Ez, Ox, Oy, Oz) {                                       \
    Ez = *(const uint4*)&eSh[bd4 + 4 * (G) + 8];                                 \
    Oz = *(const uint4*)&oSh[bd4 + 4 * (G) + 8];                                 \
    const unsigned* ap = PAq - 4 * (G);   /* = &PA[Am0 - 4G - 3], uniform */     \
    const unsigned a0 = ap[3], a1 = ap[2], a2 = ap[1], a3 = ap[0];               \
    STEP(a0, Ex.x, Ex.y, Ex.z, Ex.w, Ox.x, Ox.y, Ox.z, Ox.w);                    \
    STEP(a1, Ex.y, Ex.z, Ex.w, Ey.x, Ox.y, Ox.z, Ox.w, Oy.x);                    \
    STEP(a2, Ex.z, Ex.w, Ey.x, Ey.y, Ox.z, Ox.w, Oy.x, Oy.y);                    \
    STEP(a3, Ex.w, Ey.x, Ey.y, Ey.z, Ox.w, Oy.x, Oy.y, Oy.z);                    \
}

template <int CPB, bool PARTIAL>
__global__ __launch_bounds__(TPB) void conv_kernel(
    const unsigned* __restrict__ PApk, const unsigned* __restrict__ PEg,
    const unsigned* __restrict__ POg, unsigned* __restrict__ part,
    unsigned* __restrict__ out)
{
    __shared__ __align__(16) unsigned eSh[WPAD];
    __shared__ __align__(16) unsigned oSh[WPAD];

    int id = (int)blockIdx.x;
    int tile = 0;
#pragma unroll 1
    for (; tile < NTILE - 1; ++tile) {
        const int cnt = cnt_of(tile) / CPB;
        if (id < cnt) break;
        id -= cnt;
    }

    const int k0 = tile * TILE;
    int iMin = k0 - (MM - 1); if (iMin < 0) iMin = 0;
    const int c0 = iMin >> 8;
    const int t = (int)threadIdx.x;
    const int bd4 = 4 * t;

    unsigned acc0 = 0, acc1 = 0, acc2 = 0, acc3 = 0;
    unsigned acc4 = 0, acc5 = 0, acc6 = 0, acc7 = 0;

#pragma unroll 1
    for (int cc = 0; cc < CPB; ++cc) {
        const int i0 = (c0 + CPB * id + cc) << 8;          // chunk base limb
        const int n0 = k0 / 2 - i0 / 2 - (CHUNK / 2 - 1);  // window base (pair idx)
        const int Am0 = i0 / 2 + CHUNK / 2 - 1;            // highest PA index

        if (cc) __syncthreads();
#pragma unroll 1
        for (int s = t; s < WPAD; s += TPB) {
            const int n = n0 + s;
            const bool v = (n >= 0) && (n < NPACK);
            eSh[s] = v ? PEg[n] : 0u;
            oSh[s] = v ? POg[n] : 0u;
        }
        __syncthreads();

        const unsigned* PAq = PApk + Am0 - 3;
        uint4 E0 = *(const uint4*)&eSh[bd4];
        uint4 E1 = *(const uint4*)&eSh[bd4 + 4];
        uint4 O0 = *(const uint4*)&oSh[bd4];
        uint4 O1 = *(const uint4*)&oSh[bd4 + 4];
        uint4 E2, E3, O2, O3;

#pragma unroll
        for (int oi = 0; oi < 8; ++oi) {   // 32 groups = 128 pair-steps = 256 i
            GROUP(4 * oi + 0, E0, E1, E2, O0, O1, O2);
            GROUP(4 * oi + 1, E1, E2, E3, O1, O2, O3);
            GROUP(4 * oi + 2, E2, E3, E0, O2, O3, O0);
            GROUP(4 * oi + 3, E3, E0, E1, O3, O0, O1);
        }
    }

    if (PARTIAL) {
        unsigned* w = part + (size_t)blockIdx.x * TILE + RPT * t;
        *(uint4*)&w[0] = make_uint4(acc0, acc1, acc2, acc3);
        *(uint4*)&w[4] = make_uint4(acc4, acc5, acc6, acc7);
    } else {
        unsigned* o = out + k0 + RPT * t;
        atomicAdd(&o[0], acc0); atomicAdd(&o[1], acc1);
        atomicAdd(&o[2], acc2); atomicAdd(&o[3], acc3);
        atomicAdd(&o[4], acc4); atomicAdd(&o[5], acc5);
        atomicAdd(&o[6], acc6); atomicAdd(&o[7], acc7);
    }
}

template <int CPB>
__global__ __launch_bounds__(TPB) void reduce_kernel(
    const unsigned* __restrict__ part, unsigned* __restrict__ out)
{
    const int k = (int)blockIdx.x * TPB + (int)threadIdx.x;
    const int tile = k >> 11;
    const int u = 8 / CPB;
    const int base = (tile <= 16) ? u * tile * (tile + 1) / 2
                                  : u * (272 - (NTILE - tile) * (NTILE + 1 - tile) / 2);
    const int cnt = cnt_of(tile) / CPB;

    const unsigned* p = part + (size_t)base * TILE + (k & (TILE - 1));
    unsigned s0 = 0, s1 = 0, s2 = 0, s3 = 0;
    int c = 0;
#pragma unroll 1
    for (; c + 4 <= cnt; c += 4) {   // independent chains pipeline the loads
        s0 += p[(size_t)(c + 0) * TILE]; s1 += p[(size_t)(c + 1) * TILE];
        s2 += p[(size_t)(c + 2) * TILE]; s3 += p[(size_t)(c + 3) * TILE];
    }
    for (; c < cnt; ++c) s0 += p[(size_t)c * TILE];
    out[k] = s0 + s1 + s2 + s3;
}

extern "C" void kernel_launch(void* const* d_in, const int* in_sizes, int n_in,
                              void* d_out, int out_size, void* d_ws, size_t ws_size,
                              hipStream_t stream)
{
    const int* A = (const int*)d_in[0];
    const int* B = (const int*)d_in[1];
    unsigned* out = (unsigned*)d_out;
    unsigned* ws = (unsigned*)d_ws;

    const size_t packB = (size_t)P_OFS * 4;
    const size_t need1 = packB + (size_t)2176 * TILE * 4;  // ~18.0 MB
    const size_t need2 = packB + (size_t)1088 * TILE * 4;  // ~9.1 MB
    const size_t need4 = packB + (size_t)544 * TILE * 4;   // ~4.65 MB

    pack_kernel<<<(NPACK + TPB - 1) / TPB, TPB, 0, stream>>>(A, B, ws);

    const unsigned* pa = ws + PA_OFS;
    const unsigned* pe = ws + PE_OFS;
    const unsigned* po = ws + PO_OFS;
    unsigned* part = ws + P_OFS;

    if (ws_size >= need1) {
        conv_kernel<1, true><<<2176, TPB, 0, stream>>>(pa, pe, po, part, out);
        reduce_kernel<1><<<(2 * MM) / TPB, TPB, 0, stream>>>(part, out);
    } else if (ws_size >= need2) {
        conv_kernel<2, true><<<1088, TPB, 0, stream>>>(pa, pe, po, part, out);
        reduce_kernel<2><<<(2 * MM) / TPB, TPB, 0, stream>>>(part, out);
    } else if (ws_size >= need4) {
        conv_kernel<4, true><<<544, TPB, 0, stream>>>(pa, pe, po, part, out);
        reduce_kernel<4><<<(2 * MM) / TPB, TPB, 0, stream>>>(part, out);
    } else {
        hipMemsetAsync(d_out, 0, (size_t)out_size * sizeof(int), stream);
        conv_kernel<2, false><<<1088, TPB, 0, stream>>>(pa, pe, po, nullptr, out);
    }
}

// Round 6
// 43.778 us; speedup vs baseline: 5.0509x; 1.0220x over previous
//
#include <hip/hip_runtime.h>

#define MM     32768
#define TPB    256
#define RPT    8                    // bins per thread
#define TILE   2048                 // bins per tile
#define NTILE  32
#define CHUNK  256                  // i-limbs per chunk (=128 pairs)
#define NPACK  (MM / 2 + 1)         // 16385 packed entries (edge pad)
#define WPAD   1160                 // window dwords per parity (1152 live + pad)
#define APAD   136                  // A-quad dwords (128 live + 2-quad lookahead pad)
#define PA_OFS 0                    // ws dword offsets
#define PE_OFS (MM / 2)             // 16384
#define PO_OFS (PE_OFS + NPACK)     // 32769
#define P_OFS  49408                // partials base (256-aligned dwords)

// Per-tile chunk count: 8(t+1) for t<16 else 8(32-t); sum = 2176.
__device__ __host__ __forceinline__ int cnt_of(int t) {
    return (t < NTILE / 2) ? 8 * (t + 1) : 8 * (NTILE - t);
}

typedef unsigned short ushort2e __attribute__((ext_vector_type(2)));

// 2 exact u16 MACs accumulated mod 2^32 (u32 wrap == the int32 the harness compares).
__device__ __forceinline__ unsigned DOT2(unsigned a, unsigned b, unsigned c) {
#if __has_builtin(__builtin_amdgcn_udot2)
    return __builtin_amdgcn_udot2(__builtin_bit_cast(ushort2e, a),
                                  __builtin_bit_cast(ushort2e, b), c, false);
#else
    return c + (a & 0xFFFFu) * (b & 0xFFFFu) + (a >> 16) * (b >> 16);
#endif
}

// PA[m]=(lo A[2m], hi A[2m+1]); PE[n]=(lo B[2n], hi B[2n-1]); PO[n]=(lo B[2n+1], hi B[2n]).
__global__ __launch_bounds__(TPB) void pack_kernel(
    const int* __restrict__ A, const int* __restrict__ B, unsigned* __restrict__ ws)
{
    const int e = (int)blockIdx.x * TPB + (int)threadIdx.x;
    if (e < MM / 2)
        ws[PA_OFS + e] = (unsigned)A[2 * e] | ((unsigned)A[2 * e + 1] << 16);
    if (e < NPACK) {
        const unsigned elo = (e < MM / 2) ? (unsigned)B[2 * e] : 0u;
        const unsigned ehi = (e >= 1) ? (unsigned)B[2 * e - 1] : 0u;
        ws[PE_OFS + e] = elo | (ehi << 16);
        unsigned olo = 0u, ohi = 0u;
        if (e < MM / 2) { olo = (unsigned)B[2 * e + 1]; ohi = (unsigned)B[2 * e]; }
        ws[PO_OFS + e] = olo | (ohi << 16);
    }
}

// Even bin k=2K: acc += dot2(PA[m], PE[K-m]); odd k=2K+1: dot2(PA[m], PO[K-m]).
// Window local idx = 4t + r/2 + j (j = Am0 - m); A broadcast: aSh[j] = PA[Am0-j].
#define STEP(a, e0, e1, e2, e3, o0, o1, o2, o3)                                  \
    acc0 = DOT2(a, e0, acc0); acc2 = DOT2(a, e1, acc2);                          \
    acc4 = DOT2(a, e2, acc4); acc6 = DOT2(a, e3, acc6);                          \
    acc1 = DOT2(a, o0, acc1); acc3 = DOT2(a, o1, acc3);                          \
    acc5 = DOT2(a, o2, acc5); acc7 = DOT2(a, o3, acc7);

// Group G (j = 4G+d, d=0..3): rows use E-quads (G,G+1), A-quad G (uniform
// broadcast ds_read, conflict-free); prefetch quad G+2 of E, O, A.
#define GROUP(G, Ex, Ey, Ez, Ox, Oy, Oz, Au, Al) {                               \
    Ez = *(const uint4*)&eSh[bd4 + 4 * (G) + 8];                                 \
    Oz = *(const uint4*)&oSh[bd4 + 4 * (G) + 8];                                 \
    Al = *(const uint4*)&aSh[4 * (G) + 8];                                       \
    STEP(Au.x, Ex.x, Ex.y, Ex.z, Ex.w, Ox.x, Ox.y, Ox.z, Ox.w);                  \
    STEP(Au.y, Ex.y, Ex.z, Ex.w, Ey.x, Ox.y, Ox.z, Ox.w, Oy.x);                  \
    STEP(Au.z, Ex.z, Ex.w, Ey.x, Ey.y, Ox.z, Ox.w, Oy.x, Oy.y);                  \
    STEP(Au.w, Ex.w, Ey.x, Ey.y, Ey.z, Ox.w, Oy.x, Oy.y, Oy.z);                  \
}

template <int CPB, bool PARTIAL>
__global__ __launch_bounds__(TPB) void conv_kernel(
    const unsigned* __restrict__ PApk, const unsigned* __restrict__ PEg,
    const unsigned* __restrict__ POg, unsigned* __restrict__ part,
    unsigned* __restrict__ out)
{
    __shared__ __align__(16) unsigned eSh[WPAD];
    __shared__ __align__(16) unsigned oSh[WPAD];
    __shared__ __align__(16) unsigned aSh[APAD];

    int id = (int)blockIdx.x;
    int tile = 0;
#pragma unroll 1
    for (; tile < NTILE - 1; ++tile) {
        const int cnt = cnt_of(tile) / CPB;
        if (id < cnt) break;
        id -= cnt;
    }

    const int k0 = tile * TILE;
    int iMin = k0 - (MM - 1); if (iMin < 0) iMin = 0;
    const int c0 = iMin >> 8;
    const int t = (int)threadIdx.x;
    const int bd4 = 4 * t;

    unsigned acc0 = 0, acc1 = 0, acc2 = 0, acc3 = 0;
    unsigned acc4 = 0, acc5 = 0, acc6 = 0, acc7 = 0;

#pragma unroll 1
    for (int cc = 0; cc < CPB; ++cc) {
        const int i0 = (c0 + CPB * id + cc) << 8;          // chunk base limb
        const int n0 = k0 / 2 - i0 / 2 - (CHUNK / 2 - 1);  // window base (pair idx)
        const int Am0 = i0 / 2 + CHUNK / 2 - 1;            // highest PA index

        if (cc) __syncthreads();
#pragma unroll 1
        for (int s = t; s < WPAD; s += TPB) {
            const int n = n0 + s;
            const bool v = (n >= 0) && (n < NPACK);
            eSh[s] = v ? PEg[n] : 0u;
            oSh[s] = v ? POg[n] : 0u;
        }
        if (t < APAD) aSh[t] = (t < CHUNK / 2) ? PApk[Am0 - t] : 0u;
        __syncthreads();

        uint4 E0 = *(const uint4*)&eSh[bd4];
        uint4 E1 = *(const uint4*)&eSh[bd4 + 4];
        uint4 O0 = *(const uint4*)&oSh[bd4];
        uint4 O1 = *(const uint4*)&oSh[bd4 + 4];
        uint4 A0 = *(const uint4*)&aSh[0];
        uint4 A1 = *(const uint4*)&aSh[4];
        uint4 E2, E3, O2, O3, A2, A3;

#pragma unroll
        for (int oi = 0; oi < 8; ++oi) {   // 32 groups = 128 pair-steps = 256 i
            GROUP(4 * oi + 0, E0, E1, E2, O0, O1, O2, A0, A2);
            GROUP(4 * oi + 1, E1, E2, E3, O1, O2, O3, A1, A3);
            GROUP(4 * oi + 2, E2, E3, E0, O2, O3, O0, A2, A0);
            GROUP(4 * oi + 3, E3, E0, E1, O3, O0, O1, A3, A1);
        }
    }

    if (PARTIAL) {
        unsigned* w = part + (size_t)blockIdx.x * TILE + RPT * t;
        *(uint4*)&w[0] = make_uint4(acc0, acc1, acc2, acc3);
        *(uint4*)&w[4] = make_uint4(acc4, acc5, acc6, acc7);
    } else {
        unsigned* o = out + k0 + RPT * t;
        atomicAdd(&o[0], acc0); atomicAdd(&o[1], acc1);
        atomicAdd(&o[2], acc2); atomicAdd(&o[3], acc3);
        atomicAdd(&o[4], acc4); atomicAdd(&o[5], acc5);
        atomicAdd(&o[6], acc6); atomicAdd(&o[7], acc7);
    }
}

template <int CPB>
__global__ __launch_bounds__(TPB) void reduce_kernel(
    const unsigned* __restrict__ part, unsigned* __restrict__ out)
{
    const int k = (int)blockIdx.x * TPB + (int)threadIdx.x;
    const int tile = k >> 11;
    const int u = 8 / CPB;
    const int base = (tile <= 16) ? u * tile * (tile + 1) / 2
                                  : u * (272 - (NTILE - tile) * (NTILE + 1 - tile) / 2);
    const int cnt = cnt_of(tile) / CPB;

    const unsigned* p = part + (size_t)base * TILE + (k & (TILE - 1));
    unsigned s0 = 0, s1 = 0, s2 = 0, s3 = 0;
    int c = 0;
#pragma unroll 1
    for (; c + 4 <= cnt; c += 4) {   // independent chains pipeline the loads
        s0 += p[(size_t)(c + 0) * TILE]; s1 += p[(size_t)(c + 1) * TILE];
        s2 += p[(size_t)(c + 2) * TILE]; s3 += p[(size_t)(c + 3) * TILE];
    }
    for (; c < cnt; ++c) s0 += p[(size_t)c * TILE];
    out[k] = s0 + s1 + s2 + s3;
}

extern "C" void kernel_launch(void* const* d_in, const int* in_sizes, int n_in,
                              void* d_out, int out_size, void* d_ws, size_t ws_size,
                              hipStream_t stream)
{
    const int* A = (const int*)d_in[0];
    const int* B = (const int*)d_in[1];
    unsigned* out = (unsigned*)d_out;
    unsigned* ws = (unsigned*)d_ws;

    const size_t packB = (size_t)P_OFS * 4;
    const size_t need1 = packB + (size_t)2176 * TILE * 4;  // ~18.0 MB
    const size_t need2 = packB + (size_t)1088 * TILE * 4;  // ~9.1 MB
    const size_t need4 = packB + (size_t)544 * TILE * 4;   // ~4.65 MB

    pack_kernel<<<(NPACK + TPB - 1) / TPB, TPB, 0, stream>>>(A, B, ws);

    const unsigned* pa = ws + PA_OFS;
    const unsigned* pe = ws + PE_OFS;
    const unsigned* po = ws + PO_OFS;
    unsigned* part = ws + P_OFS;

    if (ws_size >= need1) {
        conv_kernel<1, true><<<2176, TPB, 0, stream>>>(pa, pe, po, part, out);
        reduce_kernel<1><<<(2 * MM) / TPB, TPB, 0, stream>>>(part, out);
    } else if (ws_size >= need2) {
        conv_kernel<2, true><<<1088, TPB, 0, stream>>>(pa, pe, po, part, out);
        reduce_kernel<2><<<(2 * MM) / TPB, TPB, 0, stream>>>(part, out);
    } else if (ws_size >= need4) {
        conv_kernel<4, true><<<544, TPB, 0, stream>>>(pa, pe, po, part, out);
        reduce_kernel<4><<<(2 * MM) / TPB, TPB, 0, stream>>>(part, out);
    } else {
        hipMemsetAsync(d_out, 0, (size_t)out_size * sizeof(int), stream);
        conv_kernel<2, false><<<1088, TPB, 0, stream>>>(pa, pe, po, nullptr, out);
    }
}